// Round 7
// baseline (51.589 us; speedup 1.0000x reference)
//
#include <hip/hip_runtime.h>
#include <stdint.h>

typedef __attribute__((ext_vector_type(8))) short short8;
typedef __attribute__((ext_vector_type(4))) float f32x4;

#define DEVI __device__ __forceinline__

DEVI ushort f2bf(float f) {
  union { float f; uint32_t u; } v; v.f = f;
  uint32_t r = v.u + 0x7fffu + ((v.u >> 16) & 1u);
  return (ushort)(r >> 16);
}

DEVI ushort4 pack4(float a, float b, float c, float d) {
  ushort4 o; o.x = f2bf(a); o.y = f2bf(b); o.z = f2bf(c); o.w = f2bf(d);
  return o;
}

// ---------------------------------------------------------------------------
// Tiny prep: cast W1 (pad 784->832 with zeros) and W2 to bf16, exactly once.
// Removes the 32-casts-per-thread-per-K-step VALU hog from the main kernel.
// ---------------------------------------------------------------------------
__global__ __launch_bounds__(256) void prep_w_kernel(
    const float* __restrict__ W1, const float* __restrict__ W2,
    ushort* __restrict__ w1b, ushort* __restrict__ w2b) {
  int t = blockIdx.x * 256 + threadIdx.x;   // 256*832 + 128*256 = 245760
  if (t < 256 * 832) {
    int r = t / 832, c = t - r * 832;
    w1b[t] = (c < 784) ? f2bf(W1[r * 784 + c]) : (ushort)0;
  } else {
    int u = t - 256 * 832;
    w2b[u] = f2bf(W2[u]);
  }
}

// ---------------------------------------------------------------------------
// Fused pipeline, one block = 32 batch rows end-to-end (BN = full 256).
// Quantum circuit collapses analytically (params dead): feats per 2x2 patch =
// [cos v0, cos v1, cos v0*cos v2, cos v1*cos v3] — block-private here, so cos
// is computed exactly once chip-wide.
//   Phase 1: h1(32x256) = relu(feats(32x832) @ w1b^T + b1) -> LDS bf16
//   Phase 2: h2(32x128) = relu(h1 @ w2b^T + b2)            -> LDS f32
//   Phase 3: logits = h2 @ W3^T + b3; log_softmax          -> out
// 256 blocks x 512 threads. Phase 1: LDS double-buffered A and B (single
// barrier per K-step) + 2-deep register prefetch, explicitly unrolled x2 so
// every buffer/set index is compile-time constant (no scratch).
// ---------------------------------------------------------------------------
#define LDB 72     // staging stride (ushort): 144B rows -> conflict-free b128
#define H1LD 280   // h1 stride (ushort): 560B rows -> <=2-way (free)

struct Stage1 {
  float2 xt, xb;   // one 2x2 patch of x
  int aval;
  uint4 bv[4];     // 4 x 8 bf16 of w1b
};

__global__ __launch_bounds__(512) void mega2_kernel(
    const float* __restrict__ x, const ushort* __restrict__ w1b,
    const float* __restrict__ b1, const ushort* __restrict__ w2b,
    const float* __restrict__ b2, const float* __restrict__ W3,
    const float* __restrict__ b3, float* __restrict__ out) {
  __shared__ __align__(16) ushort As[2][32 * LDB];    //   9216 B
  __shared__ __align__(16) ushort Bs[2][256 * LDB];   //  73728 B
  __shared__ __align__(16) ushort h1t[32 * H1LD];     //  17920 B (h2f overlays)
  __shared__ __align__(16) float W3s[1280];           //   5120 B  (sum 105984)

  const int tid = threadIdx.x;
  const int lane = tid & 63;
  const int w = tid >> 6;               // 8 waves; wave w owns cols w*32 (ph1)
  const int m0g = blockIdx.x * 32;

  const int arow = tid >> 4, pl = tid & 15;   // A staging: 32 rows x 16 patches

  // ---------------- Phase 1 ----------------
  auto loadT1 = [&](Stage1& S, int kt) {
    const int q = kt * 16 + pl;
    S.aval = (q < 196);
    if (S.aval) {
      const int i = q / 14, j = q - i * 14;
      const float* p = x + (size_t)(m0g + arow) * 784 + i * 56 + j * 2;
      S.xt = *(const float2*)p;
      S.xb = *(const float2*)(p + 28);
    }
    const int k0 = kt * 64;
#pragma unroll
    for (int c = 0; c < 4; ++c) {
      const int flat = c * 512 + tid, r = flat >> 3, s = flat & 7;
      S.bv[c] = *(const uint4*)(w1b + (size_t)r * 832 + k0 + s * 8);
    }
  };
  auto writeT1 = [&](int buf, const Stage1& S) {
    if (S.aval) {
      float c0 = __cosf(S.xt.x), c1 = __cosf(S.xt.y);
      float c2 = __cosf(S.xb.x), c3 = __cosf(S.xb.y);
      *(ushort4*)(&As[buf][arow * LDB + pl * 4]) = pack4(c0, c1, c0 * c2, c1 * c3);
    } else {
      ushort4 z; z.x = 0; z.y = 0; z.z = 0; z.w = 0;
      *(ushort4*)(&As[buf][arow * LDB + pl * 4]) = z;
    }
#pragma unroll
    for (int c = 0; c < 4; ++c) {
      const int flat = c * 512 + tid, r = flat >> 3, s = flat & 7;
      *(uint4*)(&Bs[buf][r * LDB + s * 8]) = S.bv[c];
    }
  };

  f32x4 acc[2][2];
#pragma unroll
  for (int m = 0; m < 2; ++m)
#pragma unroll
    for (int n = 0; n < 2; ++n) {
      f32x4 z = {0.f, 0.f, 0.f, 0.f};
      acc[m][n] = z;
    }

  auto mma1 = [&](int buf) {
#pragma unroll
    for (int ks = 0; ks < 2; ++ks) {
      short8 af[2], bf[2];
#pragma unroll
      for (int m = 0; m < 2; ++m)
        af[m] = *(const short8*)(&As[buf][(m * 16 + (lane & 15)) * LDB + ks * 32 + (lane >> 4) * 8]);
#pragma unroll
      for (int n = 0; n < 2; ++n)
        bf[n] = *(const short8*)(&Bs[buf][(w * 32 + n * 16 + (lane & 15)) * LDB + ks * 32 + (lane >> 4) * 8]);
#pragma unroll
      for (int m = 0; m < 2; ++m)
#pragma unroll
        for (int n = 0; n < 2; ++n)
          acc[m][n] = __builtin_amdgcn_mfma_f32_16x16x32_bf16(af[m], bf[n], acc[m][n], 0, 0, 0);
    }
  };

  Stage1 S0, S1;
  loadT1(S0, 0);           // tile 0 -> S0
  loadT1(S1, 1);           // tile 1 -> S1
  writeT1(0, S0);          // tile 0 -> LDS buf0
  __syncthreads();

  // 13 K-steps, explicitly unrolled x2: static buf/set indices throughout.
  for (int kt = 0; kt < 13; kt += 2) {
    // even half: compute buf0 (tile kt)
    mma1(0);
    if (kt + 2 < 13) loadT1(S0, kt + 2);     // tile kt+2 -> S0 (freed)
    if (kt + 1 < 13) writeT1(1, S1);         // tile kt+1 -> buf1
    __syncthreads();
    if (kt + 1 < 13) {
      // odd half: compute buf1 (tile kt+1)
      mma1(1);
      if (kt + 3 < 13) loadT1(S1, kt + 3);   // tile kt+3 -> S1
      if (kt + 2 < 13) writeT1(0, S0);       // tile kt+2 -> buf0
      __syncthreads();
    }
  }

  // epilogue: h1 tile -> LDS bf16 (bias+relu); W3 -> LDS.
  // C/D layout: col = lane&15, row = (lane>>4)*4 + reg   [m89-verified]
#pragma unroll
  for (int n = 0; n < 2; ++n) {
    const int col = w * 32 + n * 16 + (lane & 15);
    const float bval = b1[col];
#pragma unroll
    for (int m = 0; m < 2; ++m)
#pragma unroll
      for (int r = 0; r < 4; ++r) {
        const int row = m * 16 + (lane >> 4) * 4 + r;
        h1t[row * H1LD + col] = f2bf(fmaxf(acc[m][n][r] + bval, 0.f));
      }
  }
  for (int i = tid; i < 1280; i += 512) W3s[i] = W3[i];

  // ---------------- Phase 2 ----------------
  uint4 t2[2];
  auto loadB2 = [&](int kt) {
#pragma unroll
    for (int c = 0; c < 2; ++c) {
      const int flat = c * 512 + tid, r = flat >> 3, s = flat & 7;
      t2[c] = *(const uint4*)(w2b + (size_t)r * 256 + kt * 64 + s * 8);
    }
  };
  auto writeB2 = [&](int buf) {
#pragma unroll
    for (int c = 0; c < 2; ++c) {
      const int flat = c * 512 + tid, r = flat >> 3, s = flat & 7;
      *(uint4*)(&Bs[buf][r * LDB + s * 8]) = t2[c];
    }
  };

  f32x4 acc2[2];
#pragma unroll
  for (int m = 0; m < 2; ++m) {
    f32x4 z = {0.f, 0.f, 0.f, 0.f};
    acc2[m] = z;
  }

  auto mma2 = [&](int buf, int kt) {
#pragma unroll
    for (int ks = 0; ks < 2; ++ks) {
      short8 bf = *(const short8*)(&Bs[buf][(w * 16 + (lane & 15)) * LDB + ks * 32 + (lane >> 4) * 8]);
#pragma unroll
      for (int m = 0; m < 2; ++m) {
        short8 af = *(const short8*)(&h1t[(m * 16 + (lane & 15)) * H1LD + kt * 64 + ks * 32 + (lane >> 4) * 8]);
        acc2[m] = __builtin_amdgcn_mfma_f32_16x16x32_bf16(af, bf, acc2[m], 0, 0, 0);
      }
    }
  };

  loadB2(0);
  writeB2(0);             // Bs[0] free: phase-1 loop ended with a barrier
  __syncthreads();        // h1t + W3s + Bs[0] all visible

#pragma unroll
  for (int kt = 0; kt < 4; ++kt) {        // full unroll: static buf indices
    if (kt < 3) loadB2(kt + 1);
    mma2(kt & 1, kt);
    if (kt < 3) writeB2((kt + 1) & 1);
    __syncthreads();
  }

  // h2 -> LDS f32 (overlays h1t; last loop iter ended with a barrier)
  float* h2f = (float*)h1t;   // [32][132]
  {
    const int col = w * 16 + (lane & 15);
    const float bval = b2[col];
#pragma unroll
    for (int m = 0; m < 2; ++m)
#pragma unroll
      for (int r = 0; r < 4; ++r) {
        const int row = m * 16 + (lane >> 4) * 4 + r;
        h2f[row * 132 + col] = fmaxf(acc2[m][r] + bval, 0.f);
      }
  }
  __syncthreads();

  // ---------------- Phase 3: head ----------------
  {
    const int r = tid >> 4, p = tid & 15;   // 32 rows x 16 partials
    float a10[10];
#pragma unroll
    for (int n = 0; n < 10; ++n) a10[n] = 0.f;
#pragma unroll
    for (int e = 0; e < 8; ++e) {
      const int k = e * 16 + p;
      const float hv = h2f[r * 132 + k];
#pragma unroll
      for (int n = 0; n < 10; ++n) a10[n] = fmaf(hv, W3s[n * 128 + k], a10[n]);
    }
#pragma unroll
    for (int n = 0; n < 10; ++n) {
      a10[n] += __shfl_xor(a10[n], 1);
      a10[n] += __shfl_xor(a10[n], 2);
      a10[n] += __shfl_xor(a10[n], 4);
      a10[n] += __shfl_xor(a10[n], 8);
    }
    if (p == 0) {
#pragma unroll
      for (int n = 0; n < 10; ++n) a10[n] += b3[n];
      float mx = a10[0];
#pragma unroll
      for (int n = 1; n < 10; ++n) mx = fmaxf(mx, a10[n]);
      float s = 0.f;
#pragma unroll
      for (int n = 0; n < 10; ++n) s += __expf(a10[n] - mx);
      const float lse = mx + __logf(s);
      float* po = out + (size_t)(m0g + r) * 10;
#pragma unroll
      for (int n = 0; n < 10; ++n) po[n] = a10[n] - lse;
    }
  }
}

// ---------------------------------------------------------------------------
extern "C" void kernel_launch(void* const* d_in, const int* in_sizes, int n_in,
                              void* d_out, int out_size, void* d_ws, size_t ws_size,
                              hipStream_t stream) {
  const float* x  = (const float*)d_in[0];   // (8192,1,28,28)
  // d_in[1] = params: provably unused (diagonal phases cancel in |amp|^2)
  const float* W1 = (const float*)d_in[2];
  const float* b1 = (const float*)d_in[3];
  const float* W2 = (const float*)d_in[4];
  const float* b2 = (const float*)d_in[5];
  const float* W3 = (const float*)d_in[6];
  const float* b3 = (const float*)d_in[7];
  float* out = (float*)d_out;

  char* ws = (char*)d_ws;
  ushort* w1b = (ushort*)(ws);             // 256 x 832 bf16 (425984 B)
  ushort* w2b = (ushort*)(ws + 425984);    // 128 x 256 bf16 (65536 B)

  hipLaunchKernelGGL(prep_w_kernel, dim3(960), dim3(256), 0, stream, W1, W2, w1b, w2b);
  hipLaunchKernelGGL(mega2_kernel, dim3(256), dim3(512), 0, stream,
                     x, w1b, b1, w2b, b2, W3, b3, out);
}

// Round 8
// 35.507 us; speedup vs baseline: 1.4529x; 1.4529x over previous
//
#include <hip/hip_runtime.h>
#include <stdint.h>

typedef __attribute__((ext_vector_type(8))) short short8;
typedef __attribute__((ext_vector_type(4))) float f32x4;

#define DEVI __device__ __forceinline__

DEVI ushort f2bf(float f) {
  union { float f; uint32_t u; } v; v.f = f;
  uint32_t r = v.u + 0x7fffu + ((v.u >> 16) & 1u);
  return (ushort)(r >> 16);
}

DEVI ushort4 pack4(float a, float b, float c, float d) {
  ushort4 o; o.x = f2bf(a); o.y = f2bf(b); o.z = f2bf(c); o.w = f2bf(d);
  return o;
}

#define LDB 72   // staging stride (ushort): 144B rows -> conflict-free b128

// ---------------------------------------------------------------------------
// Quantum sim collapses analytically (params dead): feats per 2x2 patch =
// [cos v0, cos v1, cos v0*cos v2, cos v1*cos v3].
//
// Kernel 1: h1 = relu(feats(x) @ W1^T + b1). Feats cos + W1 f32->bf16 cast
// fused into staging (NO prep kernel — every prep-fed pipeline measured
// >=47.5us vs <=33 without). R4-champion schedule (dbuf LDS, 1 barrier per
// K-step, 1-deep reg prefetch); tiles shrunk BM 64->32 for occupancy:
// grid 1024 = 4 blocks/CU, 16 waves/CU (was 8) — the latency-hiding lever.
// ---------------------------------------------------------------------------
__global__ __launch_bounds__(256, 4) void gemm1_fused(
    const float* __restrict__ x, const float* __restrict__ W1,
    const float* __restrict__ b1, ushort* __restrict__ h1) {
  constexpr int NK = 13;    // K = 832 (784 + pad)
  __shared__ ushort As[2][32 * LDB];   //  9216 B
  __shared__ ushort Bs[2][64 * LDB];   // 18432 B   (27648 total)

  const int tid = threadIdx.x;
  const int lane = tid & 63;
  const int w = tid >> 6, wm = w >> 1, wn = w & 1;   // 4 waves: 2x2
  const int bm = blockIdx.x & 255, bn = blockIdx.x >> 8;
  const int m0 = bm * 32, n0 = bn * 64;

  const int srow = tid >> 4;        // 0..15
  const int pl = tid & 15;          // patch slot / f32x4 slot
  const int kc4 = pl * 4;

  float2 atop[2], abot[2];          // 2 rows x 1 patch of x
  float4 bw[4];                     // 4 rows x 4 cols of W1
  bool aval;

  auto loadT = [&](int kt) {
    const int q = kt * 16 + pl;
    aval = (q < 196);
    if (aval) {
      const int i = q / 14, j = q - i * 14;
      const float* px = x + i * 56 + j * 2;
#pragma unroll
      for (int c = 0; c < 2; ++c) {
        const float* p = px + (size_t)(m0 + c * 16 + srow) * 784;
        atop[c] = *(const float2*)p;
        abot[c] = *(const float2*)(p + 28);
      }
    }
    const int k0 = kt * 64;
    if (k0 + kc4 < 784) {
#pragma unroll
      for (int c = 0; c < 4; ++c)
        bw[c] = *(const float4*)(W1 + (size_t)(n0 + c * 16 + srow) * 784 + k0 + kc4);
    } else {
#pragma unroll
      for (int c = 0; c < 4; ++c) bw[c] = make_float4(0.f, 0.f, 0.f, 0.f);
    }
  };

  auto writeT = [&](int buf) {
    if (aval) {
#pragma unroll
      for (int c = 0; c < 2; ++c) {
        float c0 = __cosf(atop[c].x), c1 = __cosf(atop[c].y);
        float c2 = __cosf(abot[c].x), c3 = __cosf(abot[c].y);
        *(ushort4*)(&As[buf][(c * 16 + srow) * LDB + pl * 4]) =
            pack4(c0, c1, c0 * c2, c1 * c3);
      }
    } else {
      ushort4 z; z.x = 0; z.y = 0; z.z = 0; z.w = 0;
#pragma unroll
      for (int c = 0; c < 2; ++c)
        *(ushort4*)(&As[buf][(c * 16 + srow) * LDB + pl * 4]) = z;
    }
#pragma unroll
    for (int c = 0; c < 4; ++c)
      *(ushort4*)(&Bs[buf][(c * 16 + srow) * LDB + kc4]) =
          pack4(bw[c].x, bw[c].y, bw[c].z, bw[c].w);
  };

  f32x4 acc[2];                     // wave tile 16 x 32 (MF=1, NF=2)
#pragma unroll
  for (int n = 0; n < 2; ++n) {
    f32x4 z = {0.f, 0.f, 0.f, 0.f};
    acc[n] = z;
  }

  auto mma = [&](int buf) {
#pragma unroll
    for (int ks = 0; ks < 2; ++ks) {
      short8 af = *(const short8*)(&As[buf][(wm * 16 + (lane & 15)) * LDB + ks * 32 + (lane >> 4) * 8]);
#pragma unroll
      for (int n = 0; n < 2; ++n) {
        short8 bf = *(const short8*)(&Bs[buf][(wn * 32 + n * 16 + (lane & 15)) * LDB + ks * 32 + (lane >> 4) * 8]);
        acc[n] = __builtin_amdgcn_mfma_f32_16x16x32_bf16(af, bf, acc[n], 0, 0, 0);
      }
    }
  };

  loadT(0);
  writeT(0);
  __syncthreads();
  int cur = 0;
  for (int kt = 0; kt < NK; ++kt) {
    if (kt + 1 < NK) loadT(kt + 1);
    mma(cur);
    if (kt + 1 < NK) writeT(cur ^ 1);
    __syncthreads();
    cur ^= 1;
  }

  // C/D layout: col = lane&15, row = (lane>>4)*4 + reg   [m89-verified]
#pragma unroll
  for (int n = 0; n < 2; ++n) {
    const int colg = n0 + wn * 32 + n * 16 + (lane & 15);
    const float bval = b1[colg];
#pragma unroll
    for (int r = 0; r < 4; ++r) {
      const int rowg = m0 + wm * 16 + (lane >> 4) * 4 + r;
      h1[(size_t)rowg * 256 + colg] = f2bf(fmaxf(acc[n][r] + bval, 0.f));
    }
  }
}

// ---------------------------------------------------------------------------
// Kernel 2: h2 = relu(h1 @ W2^T + b2) (W2 cast in staging), h2 in LDS; then
// logits = h2 @ W3^T + b3, log_softmax. BM 32->16: grid 512 = 2 blocks/CU,
// 8 waves/CU (was 4). 4 waves share the 16 rows, each owns 32 of 128 cols.
// ---------------------------------------------------------------------------
__global__ __launch_bounds__(256, 2) void gemm2_head(
    const ushort* __restrict__ h1, const float* __restrict__ W2,
    const float* __restrict__ b2, const float* __restrict__ W3,
    const float* __restrict__ b3, float* __restrict__ out) {
  constexpr int NK = 4;   // K = 256, BK = 64
  __shared__ ushort As[2][16 * LDB];    //  4608 B
  __shared__ ushort Bs[2][128 * LDB];   // 36864 B
  __shared__ float h2f[16][132];        //  8448 B
  __shared__ float W3s[1280];           //  5120 B   (55040 total)

  const int tid = threadIdx.x;
  const int lane = tid & 63;
  const int w = tid >> 6;               // wave w owns cols w*32
  const int m0 = blockIdx.x * 16;

  for (int i = tid; i < 1280; i += 256) W3s[i] = W3[i];

  const bool ldA = tid < 128;
  const int ar = tid >> 3, asl = tid & 7;          // A: 16 rows x 8 slots
  const int br = tid >> 4, kc4 = (tid & 15) * 4;   // B: rows c*32+..? see loop

  uint4 av;
  float4 bw[8];
  auto loadT = [&](int kt) {
    const int k0 = kt * 64;
    if (ldA) av = *(const uint4*)(h1 + (size_t)(m0 + ar) * 256 + k0 + asl * 8);
#pragma unroll
    for (int c = 0; c < 8; ++c)
      bw[c] = *(const float4*)(W2 + (size_t)(c * 16 + br) * 256 + k0 + kc4);
  };
  auto writeT = [&](int buf) {
    if (ldA) *(uint4*)(&As[buf][ar * LDB + asl * 8]) = av;
#pragma unroll
    for (int c = 0; c < 8; ++c)
      *(ushort4*)(&Bs[buf][(c * 16 + br) * LDB + kc4]) =
          pack4(bw[c].x, bw[c].y, bw[c].z, bw[c].w);
  };

  f32x4 acc[2];
#pragma unroll
  for (int n = 0; n < 2; ++n) {
    f32x4 z = {0.f, 0.f, 0.f, 0.f};
    acc[n] = z;
  }

  auto mma = [&](int buf) {
#pragma unroll
    for (int ks = 0; ks < 2; ++ks) {
      short8 af = *(const short8*)(&As[buf][(lane & 15) * LDB + ks * 32 + (lane >> 4) * 8]);
#pragma unroll
      for (int n = 0; n < 2; ++n) {
        short8 bf = *(const short8*)(&Bs[buf][(w * 32 + n * 16 + (lane & 15)) * LDB + ks * 32 + (lane >> 4) * 8]);
        acc[n] = __builtin_amdgcn_mfma_f32_16x16x32_bf16(af, bf, acc[n], 0, 0, 0);
      }
    }
  };

  loadT(0);
  writeT(0);
  __syncthreads();
  int cur = 0;
#pragma unroll
  for (int kt = 0; kt < NK; ++kt) {
    if (kt + 1 < NK) loadT(kt + 1);
    mma(cur);
    if (kt + 1 < NK) writeT(cur ^ 1);
    __syncthreads();
    cur ^= 1;
  }

  // h2 tile -> LDS f32 (bias + relu)
#pragma unroll
  for (int n = 0; n < 2; ++n) {
    const int col = w * 32 + n * 16 + (lane & 15);
    const float bval = b2[col];
#pragma unroll
    for (int r = 0; r < 4; ++r)
      h2f[(lane >> 4) * 4 + r][col] = fmaxf(acc[n][r] + bval, 0.f);
  }
  __syncthreads();

  // head: 16 rows x 16 partials; k = e*16 + p
  {
    const int r = tid >> 4, p = tid & 15;
    float a10[10];
#pragma unroll
    for (int n = 0; n < 10; ++n) a10[n] = 0.f;
#pragma unroll
    for (int e = 0; e < 8; ++e) {
      const int k = e * 16 + p;
      const float hv = h2f[r][k];
#pragma unroll
      for (int n = 0; n < 10; ++n) a10[n] = fmaf(hv, W3s[n * 128 + k], a10[n]);
    }
#pragma unroll
    for (int n = 0; n < 10; ++n) {
      a10[n] += __shfl_xor(a10[n], 1);
      a10[n] += __shfl_xor(a10[n], 2);
      a10[n] += __shfl_xor(a10[n], 4);
      a10[n] += __shfl_xor(a10[n], 8);
    }
    if (p == 0) {
#pragma unroll
      for (int n = 0; n < 10; ++n) a10[n] += b3[n];
      float mx = a10[0];
#pragma unroll
      for (int n = 1; n < 10; ++n) mx = fmaxf(mx, a10[n]);
      float s = 0.f;
#pragma unroll
      for (int n = 0; n < 10; ++n) s += __expf(a10[n] - mx);
      const float lse = mx + __logf(s);
      float* po = out + (size_t)(m0 + r) * 10;
#pragma unroll
      for (int n = 0; n < 10; ++n) po[n] = a10[n] - lse;
    }
  }
}

// ---------------------------------------------------------------------------
extern "C" void kernel_launch(void* const* d_in, const int* in_sizes, int n_in,
                              void* d_out, int out_size, void* d_ws, size_t ws_size,
                              hipStream_t stream) {
  const float* x  = (const float*)d_in[0];   // (8192,1,28,28)
  // d_in[1] = params: provably unused (diagonal phases cancel in |amp|^2)
  const float* W1 = (const float*)d_in[2];
  const float* b1 = (const float*)d_in[3];
  const float* W2 = (const float*)d_in[4];
  const float* b2 = (const float*)d_in[5];
  const float* W3 = (const float*)d_in[6];
  const float* b3 = (const float*)d_in[7];
  float* out = (float*)d_out;

  ushort* h1 = (ushort*)d_ws;                 // 8192 x 256 bf16 (4.2 MB)

  hipLaunchKernelGGL(gemm1_fused, dim3(1024), dim3(256), 0, stream, x, W1, b1, h1);
  hipLaunchKernelGGL(gemm2_head, dim3(512), dim3(256), 0, stream, h1, W2, b2, W3, b3, out);
}

// Round 9
// 29.116 us; speedup vs baseline: 1.7718x; 1.2195x over previous
//
#include <hip/hip_runtime.h>
#include <stdint.h>

typedef __attribute__((ext_vector_type(8))) short short8;
typedef __attribute__((ext_vector_type(4))) float f32x4;

#define DEVI __device__ __forceinline__

DEVI ushort f2bf(float f) {
  union { float f; uint32_t u; } v; v.f = f;
  uint32_t r = v.u + 0x7fffu + ((v.u >> 16) & 1u);
  return (ushort)(r >> 16);
}

// HW packed f32->bf16 (RTNE, identical rounding to f2bf): 1 inst per 2 elems.
// No builtin on gfx950 (T12/m240) -> inline asm. lo -> bits[15:0].
DEVI uint32_t cvtpk(float lo, float hi) {
  uint32_t r;
  asm("v_cvt_pk_bf16_f32 %0, %1, %2" : "=v"(r) : "v"(lo), "v"(hi));
  return r;
}
DEVI uint2 pack4(float a, float b, float c, float d) {
  uint2 o; o.x = cvtpk(a, b); o.y = cvtpk(c, d);
  return o;
}

// ---------------------------------------------------------------------------
// Quantum sim collapses analytically (params provably dead):
//   feats per 2x2 patch (v0,v1,v2,v3) = [cos v0, cos v1, cos v0*cos v2,
//   cos v1*cos v3];  CNOT chains are a linear bit map; RZ phases cancel.
//
// R4-champion structure (30.9us), staging VALU cut ~2x via v_cvt_pk_bf16_f32.
// Kernel 1: h1 = relu(feats(x) @ W1^T + b1), feats cos + W1 cast fused into
// staging (no prep kernel). BM=BN=64, 512 blocks = 2 blocks/CU, dbuf LDS,
// 1 barrier per K-step, reg prefetch.
// ---------------------------------------------------------------------------
__global__ __launch_bounds__(256) void gemm1_fused(
    const float* __restrict__ x, const float* __restrict__ W1,
    const float* __restrict__ b1, ushort* __restrict__ h1) {
  constexpr int LDA = 72;   // 144B row stride -> conflict-free b128 reads
  constexpr int NK = 13;    // K = 832 (784 + pad)
  __shared__ ushort As[2][64 * LDA];
  __shared__ ushort Bs[2][64 * LDA];

  const int tid = threadIdx.x;
  const int lane = tid & 63;
  const int w = tid >> 6, wm = w >> 1, wn = w & 1;
  const int bm = blockIdx.x & 127, bn = blockIdx.x >> 7;
  const int m0 = bm * 64, n0 = bn * 64;

  const int srow = tid >> 4;        // 0..15: sub-row in each 16-row group
  const int pl = tid & 15;          // patch slot within k-tile
  const int kc4 = pl * 4;           // B k-offset

  float2 atop[4], abot[4];          // staged x values (4 rows, 1 patch)
  float4 bw[4];                     // staged W1 values (4 rows, 4 cols)

  f32x4 acc[2][2];
#pragma unroll
  for (int m = 0; m < 2; ++m)
#pragma unroll
    for (int n = 0; n < 2; ++n) {
      f32x4 z = {0.f, 0.f, 0.f, 0.f};
      acc[m][n] = z;
    }

  auto loadT = [&](int kt) {
    const int q = kt * 16 + pl;                 // patch index
    if (q < 196) {
      const int i = q / 14, j = q - i * 14;
      const float* px = x + i * 56 + j * 2;
#pragma unroll
      for (int c = 0; c < 4; ++c) {
        const float* p = px + (size_t)(m0 + c * 16 + srow) * 784;
        atop[c] = *(const float2*)p;
        abot[c] = *(const float2*)(p + 28);
      }
    }
    const int k0 = kt * 64;
    if (k0 + kc4 < 784) {
#pragma unroll
      for (int c = 0; c < 4; ++c)
        bw[c] = *(const float4*)(W1 + (size_t)(n0 + c * 16 + srow) * 784 + k0 + kc4);
    } else {
#pragma unroll
      for (int c = 0; c < 4; ++c) bw[c] = make_float4(0.f, 0.f, 0.f, 0.f);
    }
  };

  auto writeT = [&](int buf, int kt) {
    const int q = kt * 16 + pl;
    ushort* as = As[buf];
    ushort* bs = Bs[buf];
    if (q < 196) {
#pragma unroll
      for (int c = 0; c < 4; ++c) {
        float c0 = __cosf(atop[c].x), c1 = __cosf(atop[c].y);
        float c2 = __cosf(abot[c].x), c3 = __cosf(abot[c].y);
        *(uint2*)(as + (c * 16 + srow) * LDA + pl * 4) =
            pack4(c0, c1, c0 * c2, c1 * c3);
      }
    } else {
      uint2 z; z.x = 0; z.y = 0;
#pragma unroll
      for (int c = 0; c < 4; ++c)
        *(uint2*)(as + (c * 16 + srow) * LDA + pl * 4) = z;
    }
#pragma unroll
    for (int c = 0; c < 4; ++c)
      *(uint2*)(bs + (c * 16 + srow) * LDA + kc4) =
          pack4(bw[c].x, bw[c].y, bw[c].z, bw[c].w);
  };

  auto mma = [&](int buf) {
    const ushort* as = As[buf];
    const ushort* bs = Bs[buf];
#pragma unroll
    for (int ks = 0; ks < 2; ++ks) {
      short8 af[2], bf[2];
#pragma unroll
      for (int m = 0; m < 2; ++m) {
        int r = wm * 32 + m * 16 + (lane & 15);
        af[m] = *(const short8*)(as + r * LDA + ks * 32 + (lane >> 4) * 8);
      }
#pragma unroll
      for (int n = 0; n < 2; ++n) {
        int cdx = wn * 32 + n * 16 + (lane & 15);
        bf[n] = *(const short8*)(bs + cdx * LDA + ks * 32 + (lane >> 4) * 8);
      }
#pragma unroll
      for (int m = 0; m < 2; ++m)
#pragma unroll
        for (int n = 0; n < 2; ++n)
          acc[m][n] = __builtin_amdgcn_mfma_f32_16x16x32_bf16(af[m], bf[n], acc[m][n], 0, 0, 0);
    }
  };

  loadT(0);
  writeT(0, 0);
  __syncthreads();
  int cur = 0;
  for (int kt = 0; kt < NK; ++kt) {
    if (kt + 1 < NK) loadT(kt + 1);
    mma(cur);
    if (kt + 1 < NK) writeT(cur ^ 1, kt + 1);
    __syncthreads();
    cur ^= 1;
  }

  // C/D layout: col = lane&15, row = (lane>>4)*4 + reg   [m89-verified]
#pragma unroll
  for (int m = 0; m < 2; ++m)
#pragma unroll
    for (int n = 0; n < 2; ++n) {
      int colg = n0 + wn * 32 + n * 16 + (lane & 15);
      float bval = b1[colg];
#pragma unroll
      for (int r = 0; r < 4; ++r) {
        int rowg = m0 + wm * 32 + m * 16 + (lane >> 4) * 4 + r;
        h1[(size_t)rowg * 256 + colg] = f2bf(fmaxf(acc[m][n][r] + bval, 0.f));
      }
    }
}

// ---------------------------------------------------------------------------
// Kernel 2: h2 = relu(h1 @ W2^T + b2) (W2 cast in staging via cvt_pk), h2 in
// LDS; then logits = h2 @ W3^T + b3 and log_softmax. BM=32, BN=128 (full N),
// K=256 in 4 double-buffered steps; 256 blocks. [R4 champion structure]
// ---------------------------------------------------------------------------
__global__ __launch_bounds__(256) void gemm2_head(
    const ushort* __restrict__ h1, const float* __restrict__ W2,
    const float* __restrict__ b2, const float* __restrict__ W3,
    const float* __restrict__ b3, float* __restrict__ out) {
  constexpr int LDA = 72;
  constexpr int NK = 4;   // K = 256, BK = 64
  __shared__ ushort As[2][32 * LDA];
  __shared__ ushort Bs[2][128 * LDA];
  __shared__ float h2f[32][132];
  __shared__ float W3s[1280];

  const int tid = threadIdx.x;
  const int lane = tid & 63;
  const int w = tid >> 6, wm = w >> 1, wn = w & 1;
  const int m0 = blockIdx.x * 32;

  for (int i = tid; i < 1280; i += 256) W3s[i] = W3[i];

  const int ar = tid >> 3, asl = tid & 7;          // A: 32 rows x 8 slots
  const int br = tid >> 4, kc4 = (tid & 15) * 4;   // B: rows c*16+br

  uint4 av;
  float4 bw[8];

  auto loadT = [&](int kt) {
    const int k0 = kt * 64;
    av = *(const uint4*)(h1 + (size_t)(m0 + ar) * 256 + k0 + asl * 8);
#pragma unroll
    for (int c = 0; c < 8; ++c)
      bw[c] = *(const float4*)(W2 + (size_t)(c * 16 + br) * 256 + k0 + kc4);
  };
  auto writeT = [&](int buf) {
    *(uint4*)(As[buf] + ar * LDA + asl * 8) = av;
#pragma unroll
    for (int c = 0; c < 8; ++c)
      *(uint2*)(Bs[buf] + (c * 16 + br) * LDA + kc4) =
          pack4(bw[c].x, bw[c].y, bw[c].z, bw[c].w);
  };

  f32x4 acc[4];
#pragma unroll
  for (int n = 0; n < 4; ++n) {
    f32x4 z = {0.f, 0.f, 0.f, 0.f};
    acc[n] = z;
  }

  auto mma = [&](int buf) {
    const ushort* as = As[buf];
    const ushort* bs = Bs[buf];
#pragma unroll
    for (int ks = 0; ks < 2; ++ks) {
      int r = wm * 16 + (lane & 15);
      short8 af = *(const short8*)(as + r * LDA + ks * 32 + (lane >> 4) * 8);
#pragma unroll
      for (int n = 0; n < 4; ++n) {
        int cdx = wn * 64 + n * 16 + (lane & 15);
        short8 bf = *(const short8*)(bs + cdx * LDA + ks * 32 + (lane >> 4) * 8);
        acc[n] = __builtin_amdgcn_mfma_f32_16x16x32_bf16(af, bf, acc[n], 0, 0, 0);
      }
    }
  };

  loadT(0);
  writeT(0);
  __syncthreads();
  int cur = 0;
  for (int kt = 0; kt < NK; ++kt) {
    if (kt + 1 < NK) loadT(kt + 1);
    mma(cur);
    if (kt + 1 < NK) writeT(cur ^ 1);
    __syncthreads();
    cur ^= 1;
  }

  // h2 tile -> LDS with bias + relu
#pragma unroll
  for (int n = 0; n < 4; ++n) {
    int col = wn * 64 + n * 16 + (lane & 15);
    float bval = b2[col];
#pragma unroll
    for (int r = 0; r < 4; ++r)
      h2f[wm * 16 + (lane >> 4) * 4 + r][col] = fmaxf(acc[n][r] + bval, 0.f);
  }
  __syncthreads();

  // head: row r = tid>>3 (32 rows), partial p = tid&7 over k = e*8+p
  {
    int r = tid >> 3, p = tid & 7;
    float a10[10];
#pragma unroll
    for (int n = 0; n < 10; ++n) a10[n] = 0.f;
#pragma unroll
    for (int e = 0; e < 16; ++e) {
      int k = e * 8 + p;
      float hv = h2f[r][k];
#pragma unroll
      for (int n = 0; n < 10; ++n) a10[n] = fmaf(hv, W3s[n * 128 + k], a10[n]);
    }
#pragma unroll
    for (int n = 0; n < 10; ++n) {
      a10[n] += __shfl_xor(a10[n], 1);
      a10[n] += __shfl_xor(a10[n], 2);
      a10[n] += __shfl_xor(a10[n], 4);
    }
    if (p == 0) {
#pragma unroll
      for (int n = 0; n < 10; ++n) a10[n] += b3[n];
      float mx = a10[0];
#pragma unroll
      for (int n = 1; n < 10; ++n) mx = fmaxf(mx, a10[n]);
      float s = 0.f;
#pragma unroll
      for (int n = 0; n < 10; ++n) s += __expf(a10[n] - mx);
      float lse = mx + __logf(s);
      float* po = out + (size_t)(m0 + r) * 10;
#pragma unroll
      for (int n = 0; n < 10; ++n) po[n] = a10[n] - lse;
    }
  }
}

// ---------------------------------------------------------------------------
extern "C" void kernel_launch(void* const* d_in, const int* in_sizes, int n_in,
                              void* d_out, int out_size, void* d_ws, size_t ws_size,
                              hipStream_t stream) {
  const float* x  = (const float*)d_in[0];   // (8192,1,28,28)
  // d_in[1] = params: provably unused (diagonal phases cancel in |amp|^2)
  const float* W1 = (const float*)d_in[2];
  const float* b1 = (const float*)d_in[3];
  const float* W2 = (const float*)d_in[4];
  const float* b2 = (const float*)d_in[5];
  const float* W3 = (const float*)d_in[6];
  const float* b3 = (const float*)d_in[7];
  float* out = (float*)d_out;

  ushort* h1 = (ushort*)d_ws;                 // 8192 x 256 bf16 (4.2 MB)

  hipLaunchKernelGGL(gemm1_fused, dim3(512), dim3(256), 0, stream, x, W1, b1, h1);
  hipLaunchKernelGGL(gemm2_head, dim3(256), dim3(256), 0, stream, h1, W2, b2, W3, b3, out);
}